// Round 1
// baseline (3392.632 us; speedup 1.0000x reference)
//
#include <hip/hip_runtime.h>

typedef _Float16 f16x8 __attribute__((ext_vector_type(8)));
typedef float f32x4 __attribute__((ext_vector_type(4)));

#define TT 512
#define BB 128
#define II 512
#define HH 512

__device__ __forceinline__ f16x8 cvt8(f32x4 a, f32x4 b) {
  f16x8 r;
  r[0] = (_Float16)a[0]; r[1] = (_Float16)a[1];
  r[2] = (_Float16)a[2]; r[3] = (_Float16)a[3];
  r[4] = (_Float16)b[0]; r[5] = (_Float16)b[1];
  r[6] = (_Float16)b[2]; r[7] = (_Float16)b[3];
  return r;
}

// ---------------- Phase 1: xw[t,b,:] = x[t,b,:] @ W_ih^T + b ----------------
// C[M=65536][512] = X[M][512] * Wih[512][512]^T + bias, fp16 MFMA, fp32 out.
// 128x128 tile, BK=32, 4 waves each own a 64x64 quadrant.
__global__ __launch_bounds__(256) void xw_gemm(
    const float* __restrict__ X, const float* __restrict__ Wih,
    const float* __restrict__ bias, float* __restrict__ out) {
  __shared__ _Float16 As[128][40];  // +8 halves pad -> conflict-free frag reads
  __shared__ _Float16 Bs[128][40];
  const int tid = threadIdx.x;
  const int lane = tid & 63, wv = tid >> 6;
  const int l15 = lane & 15, lhi = lane >> 4;
  const int ntile = blockIdx.x & 3;   // n fast -> 4 blocks share the A panel
  const int mtile = blockIdx.x >> 2;
  const int M0 = mtile * 128, N0 = ntile * 128;
  const int wm = (wv & 1) * 64, wn = (wv >> 1) * 64;

  f32x4 acc[4][4];
#pragma unroll
  for (int ni = 0; ni < 4; ++ni) {
    const float bv = bias[N0 + wn + ni * 16 + l15];
#pragma unroll
    for (int mi = 0; mi < 4; ++mi) {
      acc[mi][ni][0] = bv; acc[mi][ni][1] = bv;
      acc[mi][ni][2] = bv; acc[mi][ni][3] = bv;
    }
  }
  const int srow = tid >> 1;          // 0..127
  const int shalf = (tid & 1) * 16;   // 0 or 16 halves

  for (int k0 = 0; k0 < II; k0 += 32) {
    const float* ax = X + (size_t)(M0 + srow) * II + k0 + shalf;
    const float* bx = Wih + (size_t)(N0 + srow) * II + k0 + shalf;
    f32x4 a0 = *(const f32x4*)ax,       a1 = *(const f32x4*)(ax + 4);
    f32x4 a2 = *(const f32x4*)(ax + 8), a3 = *(const f32x4*)(ax + 12);
    f32x4 b0 = *(const f32x4*)bx,       b1 = *(const f32x4*)(bx + 4);
    f32x4 b2 = *(const f32x4*)(bx + 8), b3 = *(const f32x4*)(bx + 12);
    *(f16x8*)&As[srow][shalf]     = cvt8(a0, a1);
    *(f16x8*)&As[srow][shalf + 8] = cvt8(a2, a3);
    *(f16x8*)&Bs[srow][shalf]     = cvt8(b0, b1);
    *(f16x8*)&Bs[srow][shalf + 8] = cvt8(b2, b3);
    __syncthreads();
    f16x8 af[4], bf[4];
#pragma unroll
    for (int mi = 0; mi < 4; ++mi) af[mi] = *(const f16x8*)&As[wm + mi * 16 + l15][lhi * 8];
#pragma unroll
    for (int ni = 0; ni < 4; ++ni) bf[ni] = *(const f16x8*)&Bs[wn + ni * 16 + l15][lhi * 8];
#pragma unroll
    for (int mi = 0; mi < 4; ++mi)
#pragma unroll
      for (int ni = 0; ni < 4; ++ni)
        acc[mi][ni] = __builtin_amdgcn_mfma_f32_16x16x32_f16(af[mi], bf[ni], acc[mi][ni], 0, 0, 0);
    __syncthreads();
  }
#pragma unroll
  for (int mi = 0; mi < 4; ++mi)
#pragma unroll
    for (int ni = 0; ni < 4; ++ni) {
      const size_t rbase = (size_t)(M0 + wm + mi * 16 + lhi * 4) * HH + N0 + wn + ni * 16 + l15;
#pragma unroll
      for (int r = 0; r < 4; ++r) out[rbase + (size_t)r * HH] = acc[mi][ni][r];
    }
}

// ---------------- Phase 2: h_t = tanh(xw_t + h_{t-1} @ W_hh^T) ----------------
// 8 blocks x 16 batch rows, 256 threads (4 waves, 1 wave/SIMD).
// W_hh fp16: k in [0,384) -> 96 B-fragments/wave in registers;
//            k in [384,512) -> 128 KB XOR-swizzled LDS.
// h (16x512 fp16) in swizzled LDS; xw prefetched one step ahead into regs.
__global__ __launch_bounds__(256, 1) void rnn_rec(
    const float* __restrict__ Whh, float* __restrict__ out) {
  __shared__ char lds[147456];
  char* wbase = lds;             // [512 rows][256 B] swizzled fp16 (k-local 0..127)
  char* hbase = lds + 131072;    // [16 rows][1024 B] swizzled fp16
  const int tid = threadIdx.x;
  const int lane = tid & 63, wv = tid >> 6;
  const int l15 = lane & 15, lhi = lane >> 4;
  const int row0 = blockIdx.x * 16;  // batch rows [row0, row0+16)
  const int col0 = wv * 128;         // this wave's output columns

  // ---- stage W k-chunk [384,512) into swizzled LDS (fp32 -> fp16) ----
#pragma unroll
  for (int rr = 0; rr < 2; ++rr) {
    const int r = tid * 2 + rr;  // 0..511
    const float* src = Whh + (size_t)r * HH + 384;
    char* drow = wbase + r * 256;
    const int swz = (r & 7) << 4;
#pragma unroll
    for (int j = 0; j < 16; ++j) {
      f32x4 a = *(const f32x4*)(src + j * 8);
      f32x4 b = *(const f32x4*)(src + j * 8 + 4);
      *(f16x8*)(drow + ((j * 16) ^ swz)) = cvt8(a, b);
    }
  }
  // ---- zero h (h_{-1} = 0) ----
  for (int i = tid; i < 4096; i += 256) ((unsigned int*)hbase)[i] = 0u;

  // ---- W register fragments, k in [0,384): B[k][n] = Whh[n][k] ----
  f16x8 wreg[96];
#pragma unroll
  for (int ni = 0; ni < 8; ++ni) {
    const float* wr = Whh + (size_t)(col0 + ni * 16 + l15) * HH + lhi * 8;
#pragma unroll
    for (int kj = 0; kj < 12; ++kj) {
      const float* s = wr + kj * 32;
      wreg[ni * 12 + kj] = cvt8(*(const f32x4*)s, *(const f32x4*)(s + 4));
    }
  }

  // ---- first xw prefetch (t = 0); xw lives in out[] (written by phase 1) ----
  f32x4 pref[8];
  {
    const size_t base = (size_t)(row0 + lhi * 4) * HH + col0 + l15;
#pragma unroll
    for (int ni = 0; ni < 8; ++ni)
#pragma unroll
      for (int r = 0; r < 4; ++r)
        pref[ni][r] = out[base + (size_t)r * HH + ni * 16];
  }
  __syncthreads();

  const int aswz = (l15 & 7) << 4;
  for (int t = 0; t < TT; ++t) {
    f32x4 acc[8];
#pragma unroll
    for (int ni = 0; ni < 8; ++ni) acc[ni] = pref[ni];
    // prefetch xw[t+1] (hidden under this step's MFMAs)
    if (t + 1 < TT) {
      const size_t base = (size_t)(t + 1) * (BB * HH) + (size_t)(row0 + lhi * 4) * HH + col0 + l15;
#pragma unroll
      for (int ni = 0; ni < 8; ++ni)
#pragma unroll
        for (int r = 0; r < 4; ++r)
          pref[ni][r] = out[base + (size_t)r * HH + ni * 16];
    }
    // ---- h @ W^T over k: 12 register k-frags + 4 LDS k-frags ----
#pragma unroll
    for (int kj = 0; kj < 16; ++kj) {
      f16x8 af = *(const f16x8*)(hbase + l15 * 1024 + (((kj * 32 + lhi * 8) * 2) ^ aswz));
      if (kj < 12) {
#pragma unroll
        for (int ni = 0; ni < 8; ++ni)
          acc[ni] = __builtin_amdgcn_mfma_f32_16x16x32_f16(af, wreg[ni * 12 + kj], acc[ni], 0, 0, 0);
      } else {
#pragma unroll
        for (int ni = 0; ni < 8; ++ni) {
          const int wrow = col0 + ni * 16 + l15;
          f16x8 bf = *(const f16x8*)(wbase + wrow * 256 +
                        ((((kj - 12) * 32 + lhi * 8) * 2) ^ ((wrow & 7) << 4)));
          acc[ni] = __builtin_amdgcn_mfma_f32_16x16x32_f16(af, bf, acc[ni], 0, 0, 0);
        }
      }
    }
    __syncthreads();  // all waves done reading h_{t-1}
    // ---- tanh, store h_t (overwrites xw_t in out), update h in LDS ----
    const size_t obase = (size_t)t * (BB * HH) + (size_t)(row0 + lhi * 4) * HH + col0 + l15;
#pragma unroll
    for (int ni = 0; ni < 8; ++ni)
#pragma unroll
      for (int r = 0; r < 4; ++r) {
        const float v = acc[ni][r];
        const float e = __expf(2.0f * v);
        const float th = 1.0f - 2.0f / (e + 1.0f);  // tanh(v), robust at +/-inf
        out[obase + (size_t)r * HH + ni * 16] = th;
        if (t == TT - 1)
          out[(size_t)TT * BB * HH + (size_t)(row0 + lhi * 4 + r) * HH + col0 + ni * 16 + l15] = th;
        const int hrow = lhi * 4 + r;
        *(_Float16*)(hbase + hrow * 1024 +
                     (((col0 + ni * 16 + l15) * 2) ^ ((hrow & 7) << 4))) = (_Float16)th;
      }
    __syncthreads();  // h_t fully written before next step reads it
  }
}

extern "C" void kernel_launch(void* const* d_in, const int* in_sizes, int n_in,
                              void* d_out, int out_size, void* d_ws, size_t ws_size,
                              hipStream_t stream) {
  (void)in_sizes; (void)n_in; (void)out_size; (void)d_ws; (void)ws_size;
  const float* x    = (const float*)d_in[0];
  const float* w_ih = (const float*)d_in[1];
  const float* w_hh = (const float*)d_in[2];
  const float* b    = (const float*)d_in[3];
  float* out = (float*)d_out;
  // Phase 1: xw for all timesteps -> out[0 : T*B*H)
  xw_gemm<<<dim3(2048), dim3(256), 0, stream>>>(x, w_ih, b, out);
  // Phase 2: sequential recurrence, batch-parallel across 8 blocks
  rnn_rec<<<dim3(8), dim3(256), 0, stream>>>(w_hh, out);
}

// Round 2
// 1795.242 us; speedup vs baseline: 1.8898x; 1.8898x over previous
//
#include <hip/hip_runtime.h>

typedef _Float16 f16x8 __attribute__((ext_vector_type(8)));
typedef float f32x4 __attribute__((ext_vector_type(4)));

#define TT 512
#define BB 128
#define II 512
#define HH 512

__device__ __forceinline__ f16x8 cvt8(f32x4 a, f32x4 b) {
  f16x8 r;
  r[0] = (_Float16)a[0]; r[1] = (_Float16)a[1];
  r[2] = (_Float16)a[2]; r[3] = (_Float16)a[3];
  r[4] = (_Float16)b[0]; r[5] = (_Float16)b[1];
  r[6] = (_Float16)b[2]; r[7] = (_Float16)b[3];
  return r;
}

// ---------------- Phase 1: xw[t,b,:] = x[t,b,:] @ W_ih^T + b ----------------
__global__ __launch_bounds__(256) void xw_gemm(
    const float* __restrict__ X, const float* __restrict__ Wih,
    const float* __restrict__ bias, float* __restrict__ out) {
  __shared__ _Float16 As[128][40];
  __shared__ _Float16 Bs[128][40];
  const int tid = threadIdx.x;
  const int lane = tid & 63, wv = tid >> 6;
  const int l15 = lane & 15, lhi = lane >> 4;
  const int ntile = blockIdx.x & 3;
  const int mtile = blockIdx.x >> 2;
  const int M0 = mtile * 128, N0 = ntile * 128;
  const int wm = (wv & 1) * 64, wn = (wv >> 1) * 64;

  f32x4 acc[4][4];
#pragma unroll
  for (int ni = 0; ni < 4; ++ni) {
    const float bv = bias[N0 + wn + ni * 16 + l15];
#pragma unroll
    for (int mi = 0; mi < 4; ++mi) {
      acc[mi][ni][0] = bv; acc[mi][ni][1] = bv;
      acc[mi][ni][2] = bv; acc[mi][ni][3] = bv;
    }
  }
  const int srow = tid >> 1;
  const int shalf = (tid & 1) * 16;

  for (int k0 = 0; k0 < II; k0 += 32) {
    const float* ax = X + (size_t)(M0 + srow) * II + k0 + shalf;
    const float* bx = Wih + (size_t)(N0 + srow) * II + k0 + shalf;
    f32x4 a0 = *(const f32x4*)ax,       a1 = *(const f32x4*)(ax + 4);
    f32x4 a2 = *(const f32x4*)(ax + 8), a3 = *(const f32x4*)(ax + 12);
    f32x4 b0 = *(const f32x4*)bx,       b1 = *(const f32x4*)(bx + 4);
    f32x4 b2 = *(const f32x4*)(bx + 8), b3 = *(const f32x4*)(bx + 12);
    *(f16x8*)&As[srow][shalf]     = cvt8(a0, a1);
    *(f16x8*)&As[srow][shalf + 8] = cvt8(a2, a3);
    *(f16x8*)&Bs[srow][shalf]     = cvt8(b0, b1);
    *(f16x8*)&Bs[srow][shalf + 8] = cvt8(b2, b3);
    __syncthreads();
    f16x8 af[4], bf[4];
#pragma unroll
    for (int mi = 0; mi < 4; ++mi) af[mi] = *(const f16x8*)&As[wm + mi * 16 + l15][lhi * 8];
#pragma unroll
    for (int ni = 0; ni < 4; ++ni) bf[ni] = *(const f16x8*)&Bs[wn + ni * 16 + l15][lhi * 8];
#pragma unroll
    for (int mi = 0; mi < 4; ++mi)
#pragma unroll
      for (int ni = 0; ni < 4; ++ni)
        acc[mi][ni] = __builtin_amdgcn_mfma_f32_16x16x32_f16(af[mi], bf[ni], acc[mi][ni], 0, 0, 0);
    __syncthreads();
  }
#pragma unroll
  for (int mi = 0; mi < 4; ++mi)
#pragma unroll
    for (int ni = 0; ni < 4; ++ni) {
      const size_t rbase = (size_t)(M0 + wm + mi * 16 + lhi * 4) * HH + N0 + wn + ni * 16 + l15;
#pragma unroll
      for (int r = 0; r < 4; ++r) out[rbase + (size_t)r * HH] = acc[mi][ni][r];
    }
}

// ---------------- Phase 2: h_t = tanh(xw_t + h_{t-1} @ W_hh^T) ----------------
// 8 blocks x 16 batch rows, 512 threads = 8 waves (2/SIMD), each wave owns 64
// output columns. W_hh fp16: k in [0,384) -> 48 B-frags/wave in registers
// (192 VGPR, static indices after full unroll); k in [384,512) -> 128 KB
// XOR-swizzled LDS shared by all waves. h (16x512 fp16) in swizzled LDS.
// xw read / h write via separate __restrict__ views of d_out (disjoint-in-time:
// each thread consumes xw[t+1] via register dep before it overwrites it).
// Raw s_barrier with lgkmcnt-only drain: no per-step vmcnt(0) serialization.
__global__ __launch_bounds__(512, 2) void rnn_rec(
    const float* __restrict__ Whh,
    const float* __restrict__ xw,
    float* __restrict__ hout) {
  __shared__ char lds[147456];
  char* wbase = lds;             // [512 rows][256 B] swizzled fp16, k-local 0..127
  char* hbase = lds + 131072;    // [16 rows][1024 B] swizzled fp16
  const int tid = threadIdx.x;
  const int lane = tid & 63, wv = tid >> 6;   // wv 0..7
  const int l15 = lane & 15, lhi = lane >> 4;
  const int row0 = blockIdx.x * 16;
  const int col0 = wv * 64;

  // ---- stage W k-chunk [384,512) into swizzled LDS (fp32 -> fp16) ----
  // unit u = i*512+tid: row = u>>4, slot = u&15 -> lanes 0..15 cover one row
  // contiguously => conflict-free ds_write_b128 and coalesced global reads.
#pragma unroll
  for (int i = 0; i < 16; ++i) {
    const int u = i * 512 + tid;
    const int r = u >> 4;
    const int slot = u & 15;
    const float* src = Whh + (size_t)r * HH + 384 + slot * 8;
    f32x4 a = *(const f32x4*)src;
    f32x4 b = *(const f32x4*)(src + 4);
    *(f16x8*)(wbase + r * 256 + ((slot * 16) ^ ((r & 7) << 4))) = cvt8(a, b);
  }
  // ---- zero h (h_{-1} = 0) ----
  for (int i = tid; i < 4096; i += 512) ((unsigned int*)hbase)[i] = 0u;

  // ---- W register fragments, k in [0,384): B[k][n] = Whh[n][k] ----
  f16x8 wreg[48];
#pragma unroll
  for (int ni = 0; ni < 4; ++ni) {
    const float* wr = Whh + (size_t)(col0 + ni * 16 + l15) * HH + lhi * 8;
#pragma unroll
    for (int kj = 0; kj < 12; ++kj) {
      const float* s = wr + kj * 32;
      wreg[ni * 12 + kj] = cvt8(*(const f32x4*)s, *(const f32x4*)(s + 4));
    }
  }

  // ---- first xw prefetch (t = 0) ----
  f32x4 pref[4];
  {
    const size_t base = (size_t)(row0 + lhi * 4) * HH + col0 + l15;
#pragma unroll
    for (int ni = 0; ni < 4; ++ni)
#pragma unroll
      for (int r = 0; r < 4; ++r)
        pref[ni][r] = xw[base + (size_t)r * HH + ni * 16];
  }
  __syncthreads();

  // h-row swizzle f(h) = (h&7) ^ ((h>>3)<<1): distinct across the 4 lhi groups
  // of a write instruction -> conflict-free ds_write_b16; reads stay 2-way max.
  const int fa = ((l15 & 7) ^ ((l15 >> 3) << 1)) << 4;

  for (int t = 0; t < TT; ++t) {
    f32x4 acc[4];
#pragma unroll
    for (int ni = 0; ni < 4; ++ni) acc[ni] = pref[ni];
    // prefetch xw[t+1] under this step's MFMAs
    if (t + 1 < TT) {
      const size_t base = (size_t)(t + 1) * (BB * HH) + (size_t)(row0 + lhi * 4) * HH + col0 + l15;
#pragma unroll
      for (int ni = 0; ni < 4; ++ni)
#pragma unroll
        for (int r = 0; r < 4; ++r)
          pref[ni][r] = xw[base + (size_t)r * HH + ni * 16];
    }
    // ---- h @ W^T: 12 register k-frags + 4 LDS k-frags (all indices static) ----
#pragma unroll
    for (int kj = 0; kj < 12; ++kj) {
      f16x8 af = *(const f16x8*)(hbase + l15 * 1024 + ((kj * 64 + lhi * 16) ^ fa));
#pragma unroll
      for (int ni = 0; ni < 4; ++ni)
        acc[ni] = __builtin_amdgcn_mfma_f32_16x16x32_f16(af, wreg[ni * 12 + kj], acc[ni], 0, 0, 0);
    }
#pragma unroll
    for (int kj = 12; kj < 16; ++kj) {
      f16x8 af = *(const f16x8*)(hbase + l15 * 1024 + ((kj * 64 + lhi * 16) ^ fa));
#pragma unroll
      for (int ni = 0; ni < 4; ++ni) {
        const int wrow = col0 + ni * 16 + l15;
        f16x8 bf = *(const f16x8*)(wbase + wrow * 256 +
                      ((((kj - 12) * 32 + lhi * 8) * 2) ^ ((wrow & 7) << 4)));
        acc[ni] = __builtin_amdgcn_mfma_f32_16x16x32_f16(af, bf, acc[ni], 0, 0, 0);
      }
    }
    // barrier 1: all waves done READING h_{t-1} (lgkm only -- no vmcnt drain)
    asm volatile("s_waitcnt lgkmcnt(0)" ::: "memory");
    __builtin_amdgcn_s_barrier();
    __builtin_amdgcn_sched_barrier(0);
    // ---- tanh, store h_t, update h in LDS ----
    const size_t obase = (size_t)t * (BB * HH) + (size_t)(row0 + lhi * 4) * HH + col0 + l15;
#pragma unroll
    for (int ni = 0; ni < 4; ++ni)
#pragma unroll
      for (int r = 0; r < 4; ++r) {
        const float v = acc[ni][r];
        const float e = __expf(2.0f * v);
        const float th = 1.0f - 2.0f / (e + 1.0f);  // tanh(v), robust at +/-inf
        hout[obase + (size_t)r * HH + ni * 16] = th;
        if (t == TT - 1)
          hout[(size_t)TT * BB * HH + (size_t)(row0 + lhi * 4 + r) * HH + col0 + ni * 16 + l15] = th;
        const int hrow = lhi * 4 + r;
        const int fw = ((hrow & 7) ^ ((hrow >> 3) << 1)) << 4;
        *(_Float16*)(hbase + hrow * 1024 +
                     (((col0 + ni * 16 + l15) * 2) ^ fw)) = (_Float16)th;
      }
    // barrier 2: h_t fully written before next step reads it
    asm volatile("s_waitcnt lgkmcnt(0)" ::: "memory");
    __builtin_amdgcn_s_barrier();
    __builtin_amdgcn_sched_barrier(0);
  }
}

extern "C" void kernel_launch(void* const* d_in, const int* in_sizes, int n_in,
                              void* d_out, int out_size, void* d_ws, size_t ws_size,
                              hipStream_t stream) {
  (void)in_sizes; (void)n_in; (void)out_size; (void)d_ws; (void)ws_size;
  const float* x    = (const float*)d_in[0];
  const float* w_ih = (const float*)d_in[1];
  const float* w_hh = (const float*)d_in[2];
  const float* b    = (const float*)d_in[3];
  float* out = (float*)d_out;
  // Phase 1: xw for all timesteps -> out[0 : T*B*H)
  xw_gemm<<<dim3(2048), dim3(256), 0, stream>>>(x, w_ih, b, out);
  // Phase 2: sequential recurrence, batch-parallel across 8 blocks
  rnn_rec<<<dim3(8), dim3(512), 0, stream>>>(w_hh, out, out);
}